// Round 7
// baseline (80.387 us; speedup 1.0000x reference)
//
#include <hip/hip_runtime.h>

constexpr int EMB    = 300;
constexpr int EMB4   = 75;     // EMB / 4 (float4 chunks per row)
constexpr int HIDDEN = 512;
constexpr int SEQ    = 512;
constexpr int BATCH  = 1024;
constexpr int VOCAB  = 50000;
constexpr int NBUK   = 32;     // vocab buckets
constexpr int BDIV   = 1563;   // ceil(50000/32); 49999/1563 = 31
constexpr int PB     = 4;      // batches per pool block
constexpr int GFC1   = 16;     // batches per fc1 block

__device__ __forceinline__ float4 f4add(float4 a, float4 b) {
    return make_float4(a.x + b.x, a.y + b.y, a.z + b.z, a.w + b.w);
}

// ---------------- Kernel 1: bucketize tokens per batch (deterministic) -------
// (unchanged — verified) stable 32-bucket counting sort per batch.
__global__ __launch_bounds__(256) void bucketize_kernel(
    const int* __restrict__ text,      // [SEQ, BATCH]
    const int* __restrict__ lengths,   // [BATCH]
    int* __restrict__ btok,            // [BATCH, SEQ]
    int* __restrict__ boff)            // [BATCH, NBUK+1]
{
    const int wave = threadIdx.x >> 6;
    const int lane = threadIdx.x & 63;
    const int b    = blockIdx.x * 4 + wave;
    const int len  = lengths[b];
    const unsigned long long ltmask = (1ull << lane) - 1ull;

    int cnt = 0;
#pragma unroll
    for (int c = 0; c < 8; ++c) {
        const int s = c * 64 + lane;
        int k = NBUK;
        if (s < len) k = text[(size_t)s * BATCH + b] / BDIV;
        for (int kk = 0; kk < NBUK; ++kk) {
            const unsigned long long m = __ballot(k == kk);
            if (lane == kk) cnt += __popcll(m);
        }
    }
    int incl = cnt;
#pragma unroll
    for (int off = 1; off < 32; off <<= 1) {
        const int v = __shfl_up(incl, off);
        if (lane >= off && lane < NBUK) incl += v;
    }
    const int excl = incl - cnt;
    if (lane < NBUK)  boff[b * (NBUK + 1) + lane] = excl;
    if (lane == NBUK - 1) boff[b * (NBUK + 1) + NBUK] = incl;

    int base = excl;
#pragma unroll
    for (int c = 0; c < 8; ++c) {
        const int s = c * 64 + lane;
        int tok = 0, k = NBUK;
        if (s < len) { tok = text[(size_t)s * BATCH + b]; k = tok / BDIV; }
        unsigned long long mym = 0;
        int chunkcnt = 0;
        for (int kk = 0; kk < NBUK; ++kk) {
            const unsigned long long m = __ballot(k == kk);
            if (k == kk) mym = m;
            if (lane == kk) chunkcnt = __popcll(m);
        }
        const int rank = __popcll(mym & ltmask);
        const int pos  = __shfl(base, k) + rank;
        if (s < len) btok[(size_t)b * SEQ + pos] = tok;
        base += chunkcnt;
    }
}

// ---------------- Kernel 2: pool v7 — quantile-balanced, 8 half-groups -------
// Slot x of batch b handles positions [len*x/NX, len*(x+1)/NX) of the
// bucket-sorted token list: EXACTLY len/NX (+-1) tokens per slot (perfect
// balance), and (uniform tokens) the sample quantile ~= vocab slice x, so
// slot->XCD locality is preserved. 640 threads = (4 batches x 2 token-halves)
// x 80 lanes; halves take i = half, half+2, ... (stride 2) with an 8-deep
// independent-load unroll; halves combined in LDS.
__global__ __launch_bounds__(640) void pool_kernel(
    const int* __restrict__ btok,      // [BATCH, SEQ] bucket-sorted
    const int* __restrict__ lengths,   // [BATCH]
    const float* __restrict__ emb,     // [VOCAB, EMB]
    float* __restrict__ partial,       // [NX, BATCH, EMB]
    int NX)
{
    const int x  = blockIdx.x % NX;    // slot ~ XCD (round-robin dispatch)
    const int b0 = (blockIdx.x / NX) * PB;

    __shared__ int    toks[PB][SEQ];
    __shared__ int    seg[PB][2];      // lo, n
    __shared__ float4 red[PB * 2][EMB4 + 1];

    if (threadIdx.x < PB) {
        const int len = lengths[b0 + threadIdx.x];
        const int lo  = (len * x) / NX;
        const int hi  = (len * (x + 1)) / NX;
        seg[threadIdx.x][0] = lo;
        seg[threadIdx.x][1] = hi - lo;
    }
    __syncthreads();

    for (int g = 0; g < PB; ++g) {
        const int lo = seg[g][0], n = seg[g][1];
        for (int t = threadIdx.x; t < n; t += 640)
            toks[g][t] = btok[(size_t)(b0 + g) * SEQ + lo + t];
    }
    __syncthreads();

    const int hg   = threadIdx.x / 80;   // 0..7 half-group
    const int c    = threadIdx.x % 80;
    const int g    = hg >> 1;            // batch 0..3
    const int half = hg & 1;

    if (c < EMB4) {
        const int n = seg[g][1];
        float4 A = make_float4(0.f, 0.f, 0.f, 0.f);
        float4 B = A;
        int i = half;
        for (; i + 14 < n; i += 16) {    // 8 tokens, stride 2
            const int t0 = toks[g][i +  0];
            const int t1 = toks[g][i +  2];
            const int t2 = toks[g][i +  4];
            const int t3 = toks[g][i +  6];
            const int t4 = toks[g][i +  8];
            const int t5 = toks[g][i + 10];
            const int t6 = toks[g][i + 12];
            const int t7 = toks[g][i + 14];
            const float4 v0 = ((const float4*)(emb + (size_t)t0 * EMB))[c];
            const float4 v1 = ((const float4*)(emb + (size_t)t1 * EMB))[c];
            const float4 v2 = ((const float4*)(emb + (size_t)t2 * EMB))[c];
            const float4 v3 = ((const float4*)(emb + (size_t)t3 * EMB))[c];
            const float4 v4 = ((const float4*)(emb + (size_t)t4 * EMB))[c];
            const float4 v5 = ((const float4*)(emb + (size_t)t5 * EMB))[c];
            const float4 v6 = ((const float4*)(emb + (size_t)t6 * EMB))[c];
            const float4 v7 = ((const float4*)(emb + (size_t)t7 * EMB))[c];
            A = f4add(A, f4add(f4add(v0, v1), f4add(v2, v3)));
            B = f4add(B, f4add(f4add(v4, v5), f4add(v6, v7)));
        }
        for (; i + 6 < n; i += 8) {      // 4 tokens, stride 2
            const float4 v0 = ((const float4*)(emb + (size_t)toks[g][i + 0] * EMB))[c];
            const float4 v1 = ((const float4*)(emb + (size_t)toks[g][i + 2] * EMB))[c];
            const float4 v2 = ((const float4*)(emb + (size_t)toks[g][i + 4] * EMB))[c];
            const float4 v3 = ((const float4*)(emb + (size_t)toks[g][i + 6] * EMB))[c];
            A = f4add(A, f4add(f4add(v0, v1), f4add(v2, v3)));
        }
        for (; i < n; i += 2)
            B = f4add(B, ((const float4*)(emb + (size_t)toks[g][i] * EMB))[c]);
        red[hg][c] = f4add(A, B);
    }
    __syncthreads();

    if (c < EMB4 && half == 0) {
        const float4 s = f4add(red[hg][c], red[hg + 1][c]);
        ((float4*)(partial + ((size_t)x * BATCH + b0 + g) * EMB))[c] = s;
    }
}

// ---------------- Kernel 3: fused combine + fc1 + relu (unchanged) -----------
template<int NX>
__global__ __launch_bounds__(512) void fc1_kernel(
    const float* __restrict__ partial, // [NX, BATCH, EMB]
    const int* __restrict__ lengths,   // [BATCH]
    const float* __restrict__ W1,      // [EMB, HIDDEN]
    const float* __restrict__ b1,      // [HIDDEN]
    float* __restrict__ hbuf)          // [BATCH, HIDDEN]
{
    __shared__ float4 pQ[GFC1 / 4][EMB];   // 19.2 KB
    const int b0  = blockIdx.x * GFC1;
    const int tid = threadIdx.x;

    float* pQf = (float*)pQ;
    for (int i = tid; i < EMB * GFC1; i += 512) {
        const int g = i / EMB;
        const int e = i - g * EMB;
        float s = 0.f;
#pragma unroll
        for (int xx = 0; xx < NX; ++xx)
            s += partial[((size_t)xx * BATCH + b0 + g) * EMB + e];
        pQf[((g >> 2) * EMB + e) * 4 + (g & 3)] = s / (float)lengths[b0 + g];
    }
    __syncthreads();

    const int j  = blockIdx.y * 128 + (tid & 127);
    const int gs = tid >> 7;
    const float bias = b1[j];
    float4 acc = make_float4(bias, bias, bias, bias);

    for (int e = 0; e < EMB; e += 10) {
        const float w0 = W1[(size_t)(e + 0) * HIDDEN + j];
        const float w1 = W1[(size_t)(e + 1) * HIDDEN + j];
        const float w2 = W1[(size_t)(e + 2) * HIDDEN + j];
        const float w3 = W1[(size_t)(e + 3) * HIDDEN + j];
        const float w4 = W1[(size_t)(e + 4) * HIDDEN + j];
        const float w5 = W1[(size_t)(e + 5) * HIDDEN + j];
        const float w6 = W1[(size_t)(e + 6) * HIDDEN + j];
        const float w7 = W1[(size_t)(e + 7) * HIDDEN + j];
        const float w8 = W1[(size_t)(e + 8) * HIDDEN + j];
        const float w9 = W1[(size_t)(e + 9) * HIDDEN + j];
        const float4 p0 = pQ[gs][e + 0];
        const float4 p1 = pQ[gs][e + 1];
        const float4 p2 = pQ[gs][e + 2];
        const float4 p3 = pQ[gs][e + 3];
        const float4 p4 = pQ[gs][e + 4];
        const float4 p5 = pQ[gs][e + 5];
        const float4 p6 = pQ[gs][e + 6];
        const float4 p7 = pQ[gs][e + 7];
        const float4 p8 = pQ[gs][e + 8];
        const float4 p9 = pQ[gs][e + 9];
        acc.x += p0.x * w0 + p1.x * w1 + p2.x * w2 + p3.x * w3 + p4.x * w4
               + p5.x * w5 + p6.x * w6 + p7.x * w7 + p8.x * w8 + p9.x * w9;
        acc.y += p0.y * w0 + p1.y * w1 + p2.y * w2 + p3.y * w3 + p4.y * w4
               + p5.y * w5 + p6.y * w6 + p7.y * w7 + p8.y * w8 + p9.y * w9;
        acc.z += p0.z * w0 + p1.z * w1 + p2.z * w2 + p3.z * w3 + p4.z * w4
               + p5.z * w5 + p6.z * w6 + p7.z * w7 + p8.z * w8 + p9.z * w9;
        acc.w += p0.w * w0 + p1.w * w1 + p2.w * w2 + p3.w * w3 + p4.w * w4
               + p5.w * w5 + p6.w * w6 + p7.w * w7 + p8.w * w8 + p9.w * w9;
    }
    const int bb = b0 + gs * 4;
    hbuf[(size_t)(bb + 0) * HIDDEN + j] = fmaxf(acc.x, 0.f);
    hbuf[(size_t)(bb + 1) * HIDDEN + j] = fmaxf(acc.y, 0.f);
    hbuf[(size_t)(bb + 2) * HIDDEN + j] = fmaxf(acc.z, 0.f);
    hbuf[(size_t)(bb + 3) * HIDDEN + j] = fmaxf(acc.w, 0.f);
}

// ---------------- Kernel 4: fc2 (wave-per-row dot, unchanged) ----------------
__global__ __launch_bounds__(256) void fc2_kernel(
    const float* __restrict__ hbuf,    // [BATCH, HIDDEN]
    const float* __restrict__ W2,      // [HIDDEN, 2]
    const float* __restrict__ b2,      // [2]
    float* __restrict__ out)           // [BATCH, 2]
{
    const int wave = threadIdx.x >> 6;
    const int lane = threadIdx.x & 63;
    const int b    = blockIdx.x * 4 + wave;

    const float4* hrow = (const float4*)(hbuf + (size_t)b * HIDDEN);
    const float4* W2v  = (const float4*)W2;
    float s0 = 0.f, s1 = 0.f;
#pragma unroll
    for (int q = 0; q < 2; ++q) {
        const int c = lane + q * 64;
        const float4 h  = hrow[c];
        const float4 wA = W2v[2 * c + 0];
        const float4 wB = W2v[2 * c + 1];
        s0 += h.x * wA.x + h.y * wA.z + h.z * wB.x + h.w * wB.z;
        s1 += h.x * wA.y + h.y * wA.w + h.z * wB.y + h.w * wB.w;
    }
#pragma unroll
    for (int off = 32; off > 0; off >>= 1) {
        s0 += __shfl_down(s0, off);
        s1 += __shfl_down(s1, off);
    }
    if (lane == 0) {
        out[b * 2 + 0] = s0 + b2[0];
        out[b * 2 + 1] = s1 + b2[1];
    }
}

extern "C" void kernel_launch(void* const* d_in, const int* in_sizes, int n_in,
                              void* d_out, int out_size, void* d_ws, size_t ws_size,
                              hipStream_t stream) {
    const int*   text    = (const int*)d_in[0];
    const int*   lengths = (const int*)d_in[1];
    const float* emb     = (const float*)d_in[2];
    const float* W1      = (const float*)d_in[3];
    const float* b1      = (const float*)d_in[4];
    const float* W2      = (const float*)d_in[5];
    const float* b2      = (const float*)d_in[6];
    float*       out     = (float*)d_out;

    char* ws = (char*)d_ws;
    const size_t btokBytes = (size_t)BATCH * SEQ * sizeof(int);           // 2 MB
    const size_t boffBytes = (size_t)BATCH * (NBUK + 1) * sizeof(int);    // 132 KB
    const size_t poolBytes = (size_t)BATCH * EMB * sizeof(float);         // 1.2 MB
    const size_t hbufBytes = (size_t)BATCH * HIDDEN * sizeof(float);      // 2 MB

    int*   btok = (int*)ws;
    int*   boff = (int*)(ws + btokBytes);
    float* partial = (float*)(ws + btokBytes + boffBytes);

    const size_t fixed = btokBytes + boffBytes + hbufBytes;
    int NX = 1;
    if      (ws_size >= fixed + 8 * poolBytes) NX = 8;
    else if (ws_size >= fixed + 4 * poolBytes) NX = 4;
    else if (ws_size >= fixed + 2 * poolBytes) NX = 2;
    float* hbuf = (float*)(ws + btokBytes + boffBytes + (size_t)NX * poolBytes);

    bucketize_kernel<<<BATCH / 4, 256, 0, stream>>>(text, lengths, btok, boff);
    pool_kernel<<<NX * (BATCH / PB), 640, 0, stream>>>(btok, lengths, emb, partial, NX);

    dim3 fgrid(BATCH / GFC1, HIDDEN / 128);
    switch (NX) {
        case 8: fc1_kernel<8><<<fgrid, 512, 0, stream>>>(partial, lengths, W1, b1, hbuf); break;
        case 4: fc1_kernel<4><<<fgrid, 512, 0, stream>>>(partial, lengths, W1, b1, hbuf); break;
        case 2: fc1_kernel<2><<<fgrid, 512, 0, stream>>>(partial, lengths, W1, b1, hbuf); break;
        default: fc1_kernel<1><<<fgrid, 512, 0, stream>>>(partial, lengths, W1, b1, hbuf); break;
    }
    fc2_kernel<<<BATCH / 4, 256, 0, stream>>>(hbuf, W2, b2, out);
}